// Round 1
// baseline (95.459 us; speedup 1.0000x reference)
//
#include <hip/hip_runtime.h>
#include <cstdint>

#define DIM   10000
#define NCLS  100
#define BATCH 4096
#define WORDS 157      // ceil(10000 / 64)
#define NC    4        // classes per block in the compare kernel

// ---- pack query rows into bit-words, TRANSPOSED layout qp[w*BATCH + r] ----
// grid: (ceil(WORDS/4), BATCH), block 256 (= 4 waves, one word each)
__global__ void pack_rows_q(const float* __restrict__ q,
                            unsigned long long* __restrict__ qp) {
    const int lane = threadIdx.x & 63;
    const int wv   = threadIdx.x >> 6;
    const int w    = blockIdx.x * 4 + wv;
    const int r    = blockIdx.y;
    if (w >= WORDS) return;
    const int d = w * 64 + lane;
    float v = 0.0f;
    if (d < DIM) v = q[(size_t)r * DIM + d];          // 256 B coalesced per wave
    unsigned long long mask = __ballot(v > 0.5f);      // bit i = lane i
    if (lane == 0) qp[(size_t)w * BATCH + r] = mask;
}

// ---- pack am rows, row-major layout ap[c*WORDS + w] ----
// grid: (ceil(WORDS/4), NCLS), block 256
__global__ void pack_rows_am(const float* __restrict__ a,
                             unsigned long long* __restrict__ ap) {
    const int lane = threadIdx.x & 63;
    const int wv   = threadIdx.x >> 6;
    const int w    = blockIdx.x * 4 + wv;
    const int c    = blockIdx.y;
    if (w >= WORDS) return;
    const int d = w * 64 + lane;
    float v = 0.0f;
    if (d < DIM) v = a[(size_t)c * DIM + d];
    unsigned long long mask = __ballot(v > 0.5f);
    if (lane == 0) ap[(size_t)c * WORDS + w] = mask;
}

// ---- hamming distance -> matches ----
// lane = one query row; each block: 256 rows x NC classes.
// grid: (BATCH/256, NCLS/NC), block 256
__global__ void hamming_kernel(const unsigned long long* __restrict__ qp,
                               const unsigned long long* __restrict__ ap,
                               float* __restrict__ out) {
    const int r  = blockIdx.x * blockDim.x + threadIdx.x;   // query row
    const int c0 = blockIdx.y * NC;                          // class group
    int acc[NC];
#pragma unroll
    for (int j = 0; j < NC; ++j) acc[j] = 0;

    for (int w = 0; w < WORDS; ++w) {
        unsigned long long qv = qp[(size_t)w * BATCH + r];   // 512 B coalesced
#pragma unroll
        for (int j = 0; j < NC; ++j) {
            unsigned long long av = ap[(size_t)(c0 + j) * WORDS + w]; // uniform
            acc[j] += __popcll(qv ^ av);
        }
    }
#pragma unroll
    for (int j = 0; j < NC; ++j)
        out[(size_t)r * NCLS + c0 + j] = (float)(DIM - acc[j]);
}

extern "C" void kernel_launch(void* const* d_in, const int* in_sizes, int n_in,
                              void* d_out, int out_size, void* d_ws, size_t ws_size,
                              hipStream_t stream) {
    const float* q = (const float*)d_in[0];   // [4096, 10000] f32, values {0,1}
    const float* a = (const float*)d_in[1];   // [100, 10000]  f32, values {0,1}
    float* out = (float*)d_out;               // [4096, 100]   f32

    // workspace layout: ap (100*157*8 = 125,600 B) at 0; qp at 128 KiB (5.14 MB)
    unsigned long long* ap = (unsigned long long*)d_ws;
    unsigned long long* qp = (unsigned long long*)((char*)d_ws + (128u << 10));

    pack_rows_am<<<dim3((WORDS + 3) / 4, NCLS),  256, 0, stream>>>(a, ap);
    pack_rows_q <<<dim3((WORDS + 3) / 4, BATCH), 256, 0, stream>>>(q, qp);
    hamming_kernel<<<dim3(BATCH / 256, NCLS / NC), 256, 0, stream>>>(qp, ap, out);
}

// Round 2
// 74.500 us; speedup vs baseline: 1.2813x; 1.2813x over previous
//
#include <hip/hip_runtime.h>
#include <cstdint>

#define DIM    10000
#define NCLS   100
#define BATCH  4096
#define CHUNKS 40        // chunks of 256 dims per row
#define WORDS2 160       // 40 chunks * 4 words (last chunk only 16 real dims)
#define NC     4         // classes per block in the compare kernel

typedef unsigned long long u64;

// Bit layout (permuted, consistent across q and am):
//   word (c*4 + j), bit i  <-  dim (c*256 + 4*i + j)
// Pad dims (>= DIM) read as 0.0f -> bit 0 on BOTH operands -> XOR contributes 0.

// ---- pack query rows, TRANSPOSED layout qp[w*BATCH + r] ----
// grid: BATCH/4 blocks x 256 threads (4 waves); one wave per row.
__global__ __launch_bounds__(256) void pack_q(const float* __restrict__ q,
                                              u64* __restrict__ qp) {
    const int lane = threadIdx.x & 63;
    const int wv   = threadIdx.x >> 6;
    const int r    = blockIdx.x * 4 + wv;          // query row
    const float* row = q + (size_t)r * DIM;
#pragma unroll 4
    for (int c = 0; c < CHUNKS; ++c) {
        const int d = c * 256 + lane * 4;
        float4 v = make_float4(0.f, 0.f, 0.f, 0.f);
        if (d + 3 < DIM) v = *(const float4*)(row + d);   // 1 KB/wave coalesced
        u64 b0 = __ballot(v.x > 0.5f);
        u64 b1 = __ballot(v.y > 0.5f);
        u64 b2 = __ballot(v.z > 0.5f);
        u64 b3 = __ballot(v.w > 0.5f);
        if (lane < 4) {
            u64 b = (lane == 0) ? b0 : (lane == 1) ? b1 : (lane == 2) ? b2 : b3;
            qp[(size_t)(c * 4 + lane) * BATCH + r] = b;
        }
    }
}

// ---- pack am rows, row-major layout ap[c*WORDS2 + w] ----
// grid: NCLS/4 blocks x 256 threads; one wave per class row.
__global__ __launch_bounds__(256) void pack_a(const float* __restrict__ a,
                                              u64* __restrict__ ap) {
    const int lane = threadIdx.x & 63;
    const int wv   = threadIdx.x >> 6;
    const int r    = blockIdx.x * 4 + wv;          // class row
    if (r >= NCLS) return;
    const float* row = a + (size_t)r * DIM;
#pragma unroll 4
    for (int c = 0; c < CHUNKS; ++c) {
        const int d = c * 256 + lane * 4;
        float4 v = make_float4(0.f, 0.f, 0.f, 0.f);
        if (d + 3 < DIM) v = *(const float4*)(row + d);
        u64 b0 = __ballot(v.x > 0.5f);
        u64 b1 = __ballot(v.y > 0.5f);
        u64 b2 = __ballot(v.z > 0.5f);
        u64 b3 = __ballot(v.w > 0.5f);
        if (lane < 4) {
            u64 b = (lane == 0) ? b0 : (lane == 1) ? b1 : (lane == 2) ? b2 : b3;
            ap[(size_t)r * WORDS2 + c * 4 + lane] = b;
        }
    }
}

// ---- hamming distance -> matches ----
// lane = one query row; each block: 256 rows x NC classes.
// grid: (BATCH/256, NCLS/NC), block 256
__global__ __launch_bounds__(256) void hamming_kernel(const u64* __restrict__ qp,
                                                      const u64* __restrict__ ap,
                                                      float* __restrict__ out) {
    const int r  = blockIdx.x * blockDim.x + threadIdx.x;   // query row
    const int c0 = blockIdx.y * NC;                          // class group
    int acc[NC];
#pragma unroll
    for (int j = 0; j < NC; ++j) acc[j] = 0;

#pragma unroll 2
    for (int w = 0; w < WORDS2; ++w) {
        u64 qv = qp[(size_t)w * BATCH + r];                  // 512 B coalesced
#pragma unroll
        for (int j = 0; j < NC; ++j) {
            u64 av = ap[(size_t)(c0 + j) * WORDS2 + w];      // wave-uniform (scalar)
            acc[j] += __popcll(qv ^ av);
        }
    }
#pragma unroll
    for (int j = 0; j < NC; ++j)
        out[(size_t)r * NCLS + c0 + j] = (float)(DIM - acc[j]);
}

extern "C" void kernel_launch(void* const* d_in, const int* in_sizes, int n_in,
                              void* d_out, int out_size, void* d_ws, size_t ws_size,
                              hipStream_t stream) {
    const float* q = (const float*)d_in[0];   // [4096, 10000] f32, values {0,1}
    const float* a = (const float*)d_in[1];   // [100, 10000]  f32, values {0,1}
    float* out = (float*)d_out;               // [4096, 100]   f32

    // workspace: ap (100*160*8 = 128,000 B) at 0; qp (160*4096*8 = 5.24 MB) at 128 KiB
    u64* ap = (u64*)d_ws;
    u64* qp = (u64*)((char*)d_ws + (128u << 10));

    pack_a<<<dim3((NCLS + 3) / 4), 256, 0, stream>>>(a, ap);
    pack_q<<<dim3(BATCH / 4),      256, 0, stream>>>(q, qp);
    hamming_kernel<<<dim3(BATCH / 256, NCLS / NC), 256, 0, stream>>>(qp, ap, out);
}